// Round 1
// baseline (148.700 us; speedup 1.0000x reference)
//
#include <hip/hip_runtime.h>

// Strategy: the circuit after the fused (embedding + layer-0) RYs is a FIXED
// 16x16 orthogonal map U (CNOT ring, layer-1 RYs, CNOT ring) depending only on
// qweights. z = (Us)^T D (Us) = s^T M s with M = U^T D U, and s a product
// state => z reduces to an 81-coefficient multilinear form in the per-wire
// vectors e_w = (1, cos(x_w + w0_w), sin(x_w + w0_w)):
//     z = sum_p T[p0,p1,p2,p3] * prod_w e_w[p_w]
// (cos^2 t' = (1+cos 2t')/2, sin t' cos t' = sin(2t')/2, 2t' = x + w).
// Kernel 1 (one WG, once per launch): builds U -> M -> T[81] into workspace.
// Kernel 2: per 2x2 block, 4 native sin + 4 native cos + ~110 FMA Horner
// contraction (T read via wave-uniform s_loads). FC1/FC2 unchanged.

#define CNOT_GATE(CM, TM) { \
    _Pragma("unroll") \
    for (int idx = 0; idx < 16; ++idx) { \
        if ((idx & (CM)) && !(idx & (TM))) { \
            float tmp = st[idx]; st[idx] = st[idx | (TM)]; st[idx | (TM)] = tmp; \
        } \
    } }

#define RY_GATE(MASK, C, S) { \
    _Pragma("unroll") \
    for (int idx = 0; idx < 16; ++idx) { \
        if (!(idx & (MASK))) { \
            float u0 = st[idx], u1 = st[idx | (MASK)]; \
            st[idx]          = (C)*u0 - (S)*u1; \
            st[idx | (MASK)] = (S)*u0 + (C)*u1; \
        } \
    } }

__device__ __forceinline__ float gval(int p, int a, int b) {
    // per-wire quadratic reduction coefficients:
    // a_i a_j = g0*1 + g1*cos(2t') + g2*sin(2t')
    if (p == 0) return (a == b) ? 0.5f : 0.0f;
    if (p == 1) return (a == b) ? (a ? -0.5f : 0.5f) : 0.0f;
    return (a != b) ? 0.5f : 0.0f;
}

__global__ __launch_bounds__(256) void precompute_T_kernel(
    const float* __restrict__ qw, float* __restrict__ T)
{
    __shared__ float U[16][16];   // U[k][col]
    __shared__ float M[16][16];
    const int t = threadIdx.x;

    if (t < 16) {
        // apply post-embedding circuit to basis vector e_t
        float st[16];
        #pragma unroll
        for (int k = 0; k < 16; ++k) st[k] = (k == t) ? 1.0f : 0.0f;
        // layer-0 CNOT ring (wire q -> bit mask 8>>q)
        CNOT_GATE(8, 4); CNOT_GATE(4, 2); CNOT_GATE(2, 1); CNOT_GATE(1, 8);
        // layer-1 RYs (half angles), then CNOT ring
        float cw[4], sw[4];
        #pragma unroll
        for (int w = 0; w < 4; ++w) {
            cw[w] = cosf(0.5f * qw[4 + w]);
            sw[w] = sinf(0.5f * qw[4 + w]);
        }
        RY_GATE(8, cw[0], sw[0]);
        RY_GATE(4, cw[1], sw[1]);
        RY_GATE(2, cw[2], sw[2]);
        RY_GATE(1, cw[3], sw[3]);
        CNOT_GATE(8, 4); CNOT_GATE(4, 2); CNOT_GATE(2, 1); CNOT_GATE(1, 8);
        #pragma unroll
        for (int k = 0; k < 16; ++k) U[k][t] = st[k];
    }
    __syncthreads();
    {   // M[i][j] = sum_k U[k][i] * D_k * U[k][j], D_k = +1 (k<8) else -1
        const int i = t >> 4, j = t & 15;
        float m = 0.f;
        #pragma unroll
        for (int k = 0; k < 16; ++k)
            m = fmaf((k < 8 ? 1.0f : -1.0f) * U[k][i], U[k][j], m);
        M[i][j] = m;
    }
    __syncthreads();
    if (t < 81) {
        const int p0 = t / 27, p1 = (t / 9) % 3, p2 = (t / 3) % 3, p3 = t % 3;
        float acc = 0.f;
        for (int i = 0; i < 16; ++i) {
            for (int j = 0; j < 16; ++j) {
                const float w = gval(p0, (i >> 3) & 1, (j >> 3) & 1)
                              * gval(p1, (i >> 2) & 1, (j >> 2) & 1)
                              * gval(p2, (i >> 1) & 1, (j >> 1) & 1)
                              * gval(p3, i & 1, j & 1);
                if (w != 0.f) acc = fmaf(w, M[i][j], acc);
            }
        }
        T[t] = acc;
    }
}

// One workgroup (256 threads) per image (B=4096).
// t<196: z via 81-term multilinear form (SGPR-resident T) -> lz[t].
// t<240: FC1 (196->30) split 8-way per output, wave-shuffle reduce.
// t<2  : FC2 (30->2) -> out.
__global__ __launch_bounds__(256) void hybrid_qnn_kernel(
    const float* __restrict__ x,
    const float* __restrict__ qw,
    const float* __restrict__ T,
    const float* __restrict__ W1,
    const float* __restrict__ b1,
    const float* __restrict__ W2,
    const float* __restrict__ b2,
    float* __restrict__ out)
{
    __shared__ float lz[196];   // per-block expvals
    __shared__ float lh[30];    // FC1 activations

    const int img = blockIdx.x;
    const int t   = threadIdx.x;

    if (t < 196) {
        const int i = t / 14;
        const int j = t - 14 * i;
        const float* xp = x + (size_t)img * 784 + i * 56 + j * 2;
        const float2 r0 = *(const float2*)xp;          // wires 0,1
        const float2 r1 = *(const float2*)(xp + 28);   // wires 2,3

        const float a0 = r0.x + qw[0];
        const float a1 = r0.y + qw[1];
        const float a2 = r1.x + qw[2];
        const float a3 = r1.y + qw[3];
        const float C0 = __cosf(a0), S0 = __sinf(a0);
        const float C1 = __cosf(a1), S1 = __sinf(a1);
        const float C2 = __cosf(a2), S2 = __sinf(a2);
        const float C3 = __cosf(a3), S3 = __sinf(a3);

        const float e0[3] = {1.f, C0, S0};
        const float e1[3] = {1.f, C1, S1};
        const float e2[3] = {1.f, C2, S2};

        // Horner contraction over the 3x3x3x3 tensor (innermost = wire 3).
        float z = 0.f;
        #pragma unroll
        for (int p0 = 0; p0 < 3; ++p0) {
            float s1 = 0.f;
            #pragma unroll
            for (int p1 = 0; p1 < 3; ++p1) {
                float s2 = 0.f;
                #pragma unroll
                for (int p2 = 0; p2 < 3; ++p2) {
                    const int b = ((p0 * 3 + p1) * 3 + p2) * 3;
                    float s3 = fmaf(S3, T[b + 2], fmaf(C3, T[b + 1], T[b]));
                    s2 = fmaf(s3, e2[p2], s2);
                }
                s1 = fmaf(s2, e1[p1], s1);
            }
            z = fmaf(s1, e0[p0], z);
        }
        lz[t] = z;
    }
    __syncthreads();

    // FC1: h[o] = relu(sum_j z[j] * W1[j,o] + b1[o]); 8 segments per output,
    // shuffle-reduced within each lane-octet (no extra barrier).
    if (t < 240) {
        const int o   = t >> 3;   // 0..29
        const int seg = t & 7;    // 0..7
        float acc = 0.f;
        #pragma unroll
        for (int i = 0; i < 25; ++i) {
            const int j = seg * 25 + i;
            if (j < 196) acc = fmaf(lz[j], W1[j * 30 + o], acc);
        }
        acc += __shfl_down(acc, 4, 8);
        acc += __shfl_down(acc, 2, 8);
        acc += __shfl_down(acc, 1, 8);
        if (seg == 0) lh[o] = fmaxf(acc + b1[o], 0.f);
    }
    __syncthreads();

    // FC2: out = h @ W2 + b2, W2 is (30,2) row-major.
    if (t < 2) {
        float acc = b2[t];
        #pragma unroll
        for (int k = 0; k < 30; ++k)
            acc = fmaf(lh[k], W2[k * 2 + t], acc);
        out[img * 2 + t] = acc;
    }
}

extern "C" void kernel_launch(void* const* d_in, const int* in_sizes, int n_in,
                              void* d_out, int out_size, void* d_ws, size_t ws_size,
                              hipStream_t stream) {
    const float* x  = (const float*)d_in[0];
    const float* qw = (const float*)d_in[1];
    const float* W1 = (const float*)d_in[2];
    const float* b1 = (const float*)d_in[3];
    const float* W2 = (const float*)d_in[4];
    const float* b2 = (const float*)d_in[5];
    float* out = (float*)d_out;
    float* T   = (float*)d_ws;   // 81 floats

    const int B = in_sizes[0] / 784;   // 4096
    hipLaunchKernelGGL(precompute_T_kernel, dim3(1), dim3(256), 0, stream, qw, T);
    hipLaunchKernelGGL(hybrid_qnn_kernel, dim3(B), dim3(256), 0, stream,
                       x, qw, T, W1, b1, W2, b2, out);
}

// Round 2
// 87.396 us; speedup vs baseline: 1.7014x; 1.7014x over previous
//
#include <hip/hip_runtime.h>

// Strategy: the circuit after the fused (embedding + layer-0) RYs is a FIXED
// 16x16 orthogonal map U (CNOT ring, layer-1 RYs, CNOT ring) depending only on
// qweights. z = (Us)^T D (Us) = s^T M s with M = U^T D U, and s a product
// state => z reduces to an 81-coefficient multilinear form in the per-wire
// vectors e_w = (1, cos(x_w + w0_w), sin(x_w + w0_w)):
//     z = sum_p T[p0,p1,p2,p3] * prod_w e_w[p_w]
// Kernel 1 (one WG, once per launch): builds U -> M -> T[81] into workspace.
//   T-phase uses the closed form (no branchy gval double loop — that was a
//   65.9 us serial stall in round 1):
//     T[p] = (1/16) * sum_{k=0..15} (-1)^popc(k & mask1) * M[k][k ^ mask2]
//   where mask1 = wire-bits with p_w==1, mask2 = wire-bits with p_w==2.
// Kernel 2: per 2x2 block, 4 native sin + 4 native cos + ~110 FMA Horner
// contraction (T read via wave-uniform s_loads). FC1/FC2 unchanged.

#define CNOT_GATE(CM, TM) { \
    _Pragma("unroll") \
    for (int idx = 0; idx < 16; ++idx) { \
        if ((idx & (CM)) && !(idx & (TM))) { \
            float tmp = st[idx]; st[idx] = st[idx | (TM)]; st[idx | (TM)] = tmp; \
        } \
    } }

#define RY_GATE(MASK, C, S) { \
    _Pragma("unroll") \
    for (int idx = 0; idx < 16; ++idx) { \
        if (!(idx & (MASK))) { \
            float u0 = st[idx], u1 = st[idx | (MASK)]; \
            st[idx]          = (C)*u0 - (S)*u1; \
            st[idx | (MASK)] = (S)*u0 + (C)*u1; \
        } \
    } }

__global__ __launch_bounds__(256) void precompute_T_kernel(
    const float* __restrict__ qw, float* __restrict__ T)
{
    __shared__ float U[16][16];   // U[k][col]
    __shared__ float M[16][16];
    const int t = threadIdx.x;

    if (t < 16) {
        // apply post-embedding circuit to basis vector e_t
        float st[16];
        #pragma unroll
        for (int k = 0; k < 16; ++k) st[k] = (k == t) ? 1.0f : 0.0f;
        // layer-0 CNOT ring (wire q -> bit mask 8>>q)
        CNOT_GATE(8, 4); CNOT_GATE(4, 2); CNOT_GATE(2, 1); CNOT_GATE(1, 8);
        // layer-1 RYs (half angles), then CNOT ring
        float cw[4], sw[4];
        #pragma unroll
        for (int w = 0; w < 4; ++w) {
            cw[w] = cosf(0.5f * qw[4 + w]);
            sw[w] = sinf(0.5f * qw[4 + w]);
        }
        RY_GATE(8, cw[0], sw[0]);
        RY_GATE(4, cw[1], sw[1]);
        RY_GATE(2, cw[2], sw[2]);
        RY_GATE(1, cw[3], sw[3]);
        CNOT_GATE(8, 4); CNOT_GATE(4, 2); CNOT_GATE(2, 1); CNOT_GATE(1, 8);
        #pragma unroll
        for (int k = 0; k < 16; ++k) U[k][t] = st[k];
    }
    __syncthreads();
    {   // M[i][j] = sum_k U[k][i] * D_k * U[k][j], D_k = +1 (k<8) else -1
        const int i = t >> 4, j = t & 15;
        float m = 0.f;
        #pragma unroll
        for (int k = 0; k < 16; ++k)
            m = fmaf((k < 8) ? U[k][i] : -U[k][i], U[k][j], m);
        M[i][j] = m;
    }
    __syncthreads();
    if (t < 81) {
        const int p0 = t / 27, p1 = (t / 9) % 3, p2 = (t / 3) % 3, p3 = t % 3;
        // per-wire quadratic reduction, closed form over the 2^4 nonzero terms
        const int mask1 = ((p0 == 1) << 3) | ((p1 == 1) << 2) |
                          ((p2 == 1) << 1) |  (p3 == 1);
        const int mask2 = ((p0 == 2) << 3) | ((p1 == 2) << 2) |
                          ((p2 == 2) << 1) |  (p3 == 2);
        float acc = 0.f;
        #pragma unroll
        for (int k = 0; k < 16; ++k) {
            const float v = M[k][k ^ mask2];
            acc += (__popc(k & mask1) & 1) ? -v : v;
        }
        T[t] = 0.0625f * acc;
    }
}

#undef CNOT_GATE
#undef RY_GATE

// One workgroup (256 threads) per image (B=4096).
// t<196: z via 81-term multilinear form (SGPR-resident T) -> lz[t].
// t<240: FC1 (196->30) split 8-way per output, wave-shuffle reduce.
// t<2  : FC2 (30->2) -> out.
__global__ __launch_bounds__(256) void hybrid_qnn_kernel(
    const float* __restrict__ x,
    const float* __restrict__ qw,
    const float* __restrict__ T,
    const float* __restrict__ W1,
    const float* __restrict__ b1,
    const float* __restrict__ W2,
    const float* __restrict__ b2,
    float* __restrict__ out)
{
    __shared__ float lz[196];   // per-block expvals
    __shared__ float lh[30];    // FC1 activations

    const int img = blockIdx.x;
    const int t   = threadIdx.x;

    if (t < 196) {
        const int i = t / 14;
        const int j = t - 14 * i;
        const float* xp = x + (size_t)img * 784 + i * 56 + j * 2;
        const float2 r0 = *(const float2*)xp;          // wires 0,1
        const float2 r1 = *(const float2*)(xp + 28);   // wires 2,3

        const float a0 = r0.x + qw[0];
        const float a1 = r0.y + qw[1];
        const float a2 = r1.x + qw[2];
        const float a3 = r1.y + qw[3];
        const float C0 = __cosf(a0), S0 = __sinf(a0);
        const float C1 = __cosf(a1), S1 = __sinf(a1);
        const float C2 = __cosf(a2), S2 = __sinf(a2);
        const float C3 = __cosf(a3), S3 = __sinf(a3);

        const float e0[3] = {1.f, C0, S0};
        const float e1[3] = {1.f, C1, S1};
        const float e2[3] = {1.f, C2, S2};

        // Horner contraction over the 3x3x3x3 tensor (innermost = wire 3).
        float z = 0.f;
        #pragma unroll
        for (int p0 = 0; p0 < 3; ++p0) {
            float s1 = 0.f;
            #pragma unroll
            for (int p1 = 0; p1 < 3; ++p1) {
                float s2 = 0.f;
                #pragma unroll
                for (int p2 = 0; p2 < 3; ++p2) {
                    const int b = ((p0 * 3 + p1) * 3 + p2) * 3;
                    float s3 = fmaf(S3, T[b + 2], fmaf(C3, T[b + 1], T[b]));
                    s2 = fmaf(s3, e2[p2], s2);
                }
                s1 = fmaf(s2, e1[p1], s1);
            }
            z = fmaf(s1, e0[p0], z);
        }
        lz[t] = z;
    }
    __syncthreads();

    // FC1: h[o] = relu(sum_j z[j] * W1[j,o] + b1[o]); 8 segments per output,
    // shuffle-reduced within each lane-octet (no extra barrier).
    if (t < 240) {
        const int o   = t >> 3;   // 0..29
        const int seg = t & 7;    // 0..7
        float acc = 0.f;
        #pragma unroll
        for (int i = 0; i < 25; ++i) {
            const int j = seg * 25 + i;
            if (j < 196) acc = fmaf(lz[j], W1[j * 30 + o], acc);
        }
        acc += __shfl_down(acc, 4, 8);
        acc += __shfl_down(acc, 2, 8);
        acc += __shfl_down(acc, 1, 8);
        if (seg == 0) lh[o] = fmaxf(acc + b1[o], 0.f);
    }
    __syncthreads();

    // FC2: out = h @ W2 + b2, W2 is (30,2) row-major.
    if (t < 2) {
        float acc = b2[t];
        #pragma unroll
        for (int k = 0; k < 30; ++k)
            acc = fmaf(lh[k], W2[k * 2 + t], acc);
        out[img * 2 + t] = acc;
    }
}

extern "C" void kernel_launch(void* const* d_in, const int* in_sizes, int n_in,
                              void* d_out, int out_size, void* d_ws, size_t ws_size,
                              hipStream_t stream) {
    const float* x  = (const float*)d_in[0];
    const float* qw = (const float*)d_in[1];
    const float* W1 = (const float*)d_in[2];
    const float* b1 = (const float*)d_in[3];
    const float* W2 = (const float*)d_in[4];
    const float* b2 = (const float*)d_in[5];
    float* out = (float*)d_out;
    float* T   = (float*)d_ws;   // 81 floats

    const int B = in_sizes[0] / 784;   // 4096
    hipLaunchKernelGGL(precompute_T_kernel, dim3(1), dim3(256), 0, stream, qw, T);
    hipLaunchKernelGGL(hybrid_qnn_kernel, dim3(B), dim3(256), 0, stream,
                       x, qw, T, W1, b1, W2, b2, out);
}